// Round 10
// baseline (217.545 us; speedup 1.0000x reference)
//
#include <hip/hip_runtime.h>
#include <hip/hip_bf16.h>

// Problem: B=32, F_IN=64, F_OUT=64, D=512, K=64
// out[(b,o),d] = sum_{k,e} T[(b,o),(k,e)] * W[k,e,d],
// T[(b,o),(k,e)] = sum_i coeff[o,i,k] * x[b,i,e]
// R19 = R18 (best verified, 215.6 us) + T5 setprio around T-phase MFMA
// clusters (final zero-risk probe; main bursts already had it).
// Session ledger: fused pinned at ~122-124 us across 5 structurally distinct
// schedules (R9/R13/R14 = 124; R15 bank-conflict regression; R17 occupancy
// regression). 252 unified regs/wave -> hard 2 waves/SIMD; 2-phase sync
// structure is the ceiling (m233). prep ~23 us = BW floor; ~70 us others =
// fixed harness cost invariant across all configs.

#define KK 32768

typedef __attribute__((ext_vector_type(8))) short bf16x8;
typedef __attribute__((ext_vector_type(4))) float f32x4;

__device__ __forceinline__ unsigned short f2bf(float f) {
  unsigned int u = __float_as_uint(f);
  return (unsigned short)((u + 0x7FFFu + ((u >> 16) & 1u)) >> 16);  // RNE
}

__device__ __forceinline__ unsigned int pkbf2(float a, float b) {
  __hip_bfloat162 h = __float22bfloat162_rn(make_float2(a, b));  // v_cvt_pk_bf16_f32
  return *(unsigned int*)&h;
}

__device__ __forceinline__ void gld16(void* lds, const void* g) {
  __builtin_amdgcn_global_load_lds((const __attribute__((address_space(1))) void*)g,
                                   (__attribute__((address_space(3))) void*)lds,
                                   16, 0, 0);
}

#define WAIT_VM0_LG0() asm volatile("s_waitcnt vmcnt(0) lgkmcnt(0)" ::: "memory")
#define WAIT_VM4()     asm volatile("s_waitcnt vmcnt(4)" ::: "memory")
#define WAIT_LG0()     asm volatile("s_waitcnt lgkmcnt(0)" ::: "memory")
#define BARRIER()      __builtin_amdgcn_s_barrier()
#define SCHEDB()       __builtin_amdgcn_sched_barrier(0)

// ---- merged preproc + out-zero. Blocks:
//   [0,2048):    W fp32 [64 k][512 e][512 d] -> WbT bf16 [512 d][k*512+e]
//   [2048,2176): x fp32 [32 b][64 i][512 e]  -> xT bf16 [b][e][i]
//   [2176,2240): coeff fp32 [64 o][64 i][64 k] -> cb bf16 [k][o*64+i]
//   [2240,2368): zero out (4 MB, 32 KB/block, float4 stores)
__global__ __launch_bounds__(256) void prep_kern(const float* __restrict__ x,
                                                 const float* __restrict__ c,
                                                 const float* __restrict__ W,
                                                 unsigned short* __restrict__ xT,
                                                 unsigned short* __restrict__ cb,
                                                 unsigned short* __restrict__ WbT,
                                                 float* __restrict__ out) {
  __shared__ float tile[64][133];            // 34 KB
  int bx = blockIdx.x;
  int t = threadIdx.x;
  if (bx < 2048) {
    int k = bx >> 5, et = (bx >> 2) & 7, dq = bx & 3;
    const float* src = W + ((size_t)k * 512 + (size_t)et * 64) * 512 + dq * 128;
    int rr = t >> 5, c4 = t & 31;
#pragma unroll
    for (int p = 0; p < 8; p++) {
      int e = p * 8 + rr;
      *(float4*)&tile[e][c4 * 4] = *(const float4*)(src + (size_t)e * 512 + c4 * 4);
    }
    __syncthreads();
    int ch = t & 7, dr = t >> 3;
#pragma unroll
    for (int p = 0; p < 4; p++) {
      int d = p * 32 + dr, e0 = ch * 8;
      uint4 o4;
      o4.x = pkbf2(tile[e0 + 0][d], tile[e0 + 1][d]);
      o4.y = pkbf2(tile[e0 + 2][d], tile[e0 + 3][d]);
      o4.z = pkbf2(tile[e0 + 4][d], tile[e0 + 5][d]);
      o4.w = pkbf2(tile[e0 + 6][d], tile[e0 + 7][d]);
      *(uint4*)(WbT + (size_t)(dq * 128 + d) * KK + k * 512 + et * 64 + e0) = o4;
    }
  } else if (bx < 2176) {
    int bx2 = bx - 2048;
    int b = bx2 >> 2, ec = bx2 & 3;
    const float* src = x + (size_t)b * 32768 + ec * 128;
    int rr = t >> 5, c4 = t & 31;
#pragma unroll
    for (int p = 0; p < 8; p++) {
      int i = p * 8 + rr;
      *(float4*)&tile[i][c4 * 4] = *(const float4*)(src + (size_t)i * 512 + c4 * 4);
    }
    __syncthreads();
    unsigned short* dst = xT + (size_t)b * 32768 + ec * 128 * 64;
    int ch = t & 7, er = t >> 3;
#pragma unroll
    for (int p = 0; p < 4; p++) {
      int e = p * 32 + er, i0 = ch * 8;
      uint4 o4;
      o4.x = pkbf2(tile[i0 + 0][e], tile[i0 + 1][e]);
      o4.y = pkbf2(tile[i0 + 2][e], tile[i0 + 3][e]);
      o4.z = pkbf2(tile[i0 + 4][e], tile[i0 + 5][e]);
      o4.w = pkbf2(tile[i0 + 6][e], tile[i0 + 7][e]);
      *(uint4*)(dst + e * 64 + i0) = o4;
    }
  } else if (bx < 2240) {
    int rb = bx - 2176;
    unsigned short* lds = (unsigned short*)tile;
    const float* src = c + (size_t)rb * 4096;
#pragma unroll
    for (int j = 0; j < 16; j++) {
      int idx = j * 256 + t;
      int r = idx >> 6, k = idx & 63;
      lds[r * 66 + k] = f2bf(src[idx]);
    }
    __syncthreads();
#pragma unroll
    for (int j = 0; j < 16; j++) {
      int idx = j * 256 + t;
      int k = idx >> 6, r = idx & 63;
      cb[(size_t)k * 4096 + rb * 64 + r] = lds[r * 66 + k];
    }
  } else {
    // zero out: 128 blocks x 32 KB (8192 floats); thread t: 8 x float4
    float* dst = out + (size_t)(bx - 2240) * 8192;
    float4 z = {0.f, 0.f, 0.f, 0.f};
#pragma unroll
    for (int j = 0; j < 8; j++)
      *(float4*)(dst + (size_t)j * 1024 + t * 4) = z;
  }
}

// ---- fused T+GEMM (R13 body, proven 124 us): grid 512 = mt(16) x np(2) x
// ks(16); block-tile 128m x 256n, kk-slice 2048. 4 waves, 2 blocks/CU.
// Per (ec,k): T-MFMA -> B_A (vmcnt0: drains h0 loads issued a full phase ago)
// -> issue h1 loads -> As write -> B_A2 (lgkm only) -> main h0
// -> B_B (vmcnt0: drains h1, had As+h0 phase to fly) + issue next h0 -> main h1.
__global__ __launch_bounds__(256, 2) void fused_kern(const unsigned short* __restrict__ xT,
                                                     const unsigned short* __restrict__ cb,
                                                     const unsigned short* __restrict__ Bt,
                                                     float* __restrict__ out) {
  __shared__ unsigned short u[128 * 64];     // xe (per-ec) / As alias, 16 KB
  __shared__ unsigned short Bs0[128 * 64];   // d-rows 0..127, 16 KB
  __shared__ unsigned short Bs1[128 * 64];   // d-rows 128..255, 16 KB
  __shared__ unsigned short ck[4 * 64 * 64]; // 32 KB (4 k-words, whole block)
  int bx = blockIdx.x;                       // ks minor: mt-siblings co-XCD
  int ks = bx & 15, np = (bx >> 4) & 1, mt = bx >> 5;
  int m0 = mt * 128, n0 = np * 256, kw0 = ks * 4, b0 = mt * 2;
  int t = threadIdx.x;
  int wid = t >> 6, lane = t & 63, q = lane >> 4, l16 = lane & 15;
  int wmb = wid & 1;                         // m-half (= b index in T-phase)
  int wnh = wid >> 1;                        // n-half (= o-tile-pair in T-phase)
  int srow = t >> 3;                         // 0..31 staging row
  int cg = (t & 7) ^ (srow & 7);
  // ---- prologue: ck (32 KB, 8 rounds) + Bs0 for s=0 h0 (4 rounds)
  {
    const unsigned short* gc = cb + (size_t)kw0 * 4096;
#pragma unroll
    for (int j = 0; j < 8; j++) {
      int row = j * 32 + srow;               // row = kj*64 + o; row&7 == o&7
      gld16((char*)ck + (j * 256 + t) * 16, gc + (size_t)row * 64 + cg * 8);
    }
    const unsigned short* gb = Bt + (size_t)n0 * KK + (size_t)kw0 * 512; // ec=0,k=0,h0
#pragma unroll
    for (int j = 0; j < 4; j++)
      gld16((char*)Bs0 + (j * 256 + t) * 16, gb + (size_t)(j * 32 + srow) * KK + cg * 8);
  }
  f32x4 acc[4][8] = {};                      // wave 64m x 128n (nf = h*4 + nfq)
  bf16x8 ax[4][2];                           // A[m=e][k=i] frags, held per ec
#pragma unroll 1
  for (int s = 0; s < 32; s++) {
    int k = s & 3, ec = s >> 2;
    f32x4 td[4][2];                          // [et][otl], D[m=e][n=o]
    const unsigned short* ckk = ck + k * 4096;
    if (k != 0) {
      // T-phase BEFORE B_A: overlaps h0 loads still in flight
      bf16x8 bc[2][2];
#pragma unroll
      for (int otl = 0; otl < 2; otl++)
#pragma unroll
        for (int k2 = 0; k2 < 2; k2++) {
          int o = (wnh * 2 + otl) * 16 + l16;
          int s2 = (k2 * 4 + q) ^ (o & 7);
          bc[otl][k2] = *(const bf16x8*)(ckk + o * 64 + s2 * 8);
        }
      __builtin_amdgcn_s_setprio(1);         // R19: T5 on T-phase
#pragma unroll
      for (int et = 0; et < 4; et++)
#pragma unroll
        for (int otl = 0; otl < 2; otl++) {
          td[et][otl] = (f32x4){0.f, 0.f, 0.f, 0.f};
#pragma unroll
          for (int k2 = 0; k2 < 2; k2++)
            td[et][otl] = __builtin_amdgcn_mfma_f32_16x16x32_bf16(ax[et][k2], bc[otl][k2],
                                                                  td[et][otl], 0, 0, 0);
        }
      __builtin_amdgcn_s_setprio(0);
      // B_A: drains Bs0(s) loads (flew during h1(s-1)); all waves past As reads
      WAIT_VM0_LG0(); BARRIER(); SCHEDB();
      // issue h1 loads (Bs1 readers all past B_A)
      {
        const unsigned short* gb = Bt + (size_t)(n0 + 128) * KK
                                      + (size_t)(kw0 + k) * 512 + ec * 64;
#pragma unroll
        for (int j = 0; j < 4; j++)
          gld16((char*)Bs1 + (j * 256 + t) * 16, gb + (size_t)(j * 32 + srow) * KK + cg * 8);
      }
    } else {
      // B_A: drains Bs0(s) + (s=0: ck); all waves done with u (As of prev ec)
      WAIT_VM0_LG0(); BARRIER(); SCHEDB();
      // stage xe(ec) into u, then issue h1 loads
#pragma unroll
      for (int j = 0; j < 4; j++) {
        int row = j * 32 + srow;
        int bl = row >> 6, el = row & 63;
        gld16((char*)u + (j * 256 + t) * 16,
              xT + (size_t)(b0 + bl) * 32768 + (size_t)(ec * 64 + el) * 64 + cg * 8);
      }
      {
        const unsigned short* gb = Bt + (size_t)(n0 + 128) * KK
                                      + (size_t)kw0 * 512 + ec * 64;
#pragma unroll
        for (int j = 0; j < 4; j++)
          gld16((char*)Bs1 + (j * 256 + t) * 16, gb + (size_t)(j * 32 + srow) * KK + cg * 8);
      }
      WAIT_VM4(); BARRIER(); SCHEDB();       // xe ready (4 Bs1 loads remain in flight)
      // ax frags for this ec
#pragma unroll
      for (int et = 0; et < 4; et++)
#pragma unroll
        for (int k2 = 0; k2 < 2; k2++) {
          int row = wmb * 64 + et * 16 + l16;
          int s2 = (k2 * 4 + q) ^ (row & 7);
          ax[et][k2] = *(const bf16x8*)(u + row * 64 + s2 * 8);
        }
      // T-phase (k=0)
      bf16x8 bc[2][2];
#pragma unroll
      for (int otl = 0; otl < 2; otl++)
#pragma unroll
        for (int k2 = 0; k2 < 2; k2++) {
          int o = (wnh * 2 + otl) * 16 + l16;
          int s2 = (k2 * 4 + q) ^ (o & 7);
          bc[otl][k2] = *(const bf16x8*)(ckk + o * 64 + s2 * 8);
        }
      __builtin_amdgcn_s_setprio(1);         // R19: T5 on T-phase
#pragma unroll
      for (int et = 0; et < 4; et++)
#pragma unroll
        for (int otl = 0; otl < 2; otl++) {
          td[et][otl] = (f32x4){0.f, 0.f, 0.f, 0.f};
#pragma unroll
          for (int k2 = 0; k2 < 2; k2++)
            td[et][otl] = __builtin_amdgcn_mfma_f32_16x16x32_bf16(ax[et][k2], bc[otl][k2],
                                                                  td[et][otl], 0, 0, 0);
        }
      __builtin_amdgcn_s_setprio(0);
      // RACE FIX (R13): all waves must finish their ax reads of u before ANY
      // wave overwrites u with As (waves 0/2 share rows 0..63, 1/3 share
      // 64..127). The 4 Bs1 gld16 stay in flight (lgkm-only wait).
      WAIT_LG0(); BARRIER(); SCHEDB();
    }
    // write As (alias u): row = wmb*64 + (wnh*2+otl)*16 + l16 (bo), col e
#pragma unroll
    for (int et = 0; et < 4; et++)
#pragma unroll
      for (int otl = 0; otl < 2; otl++) {
        int row = wmb * 64 + (wnh * 2 + otl) * 16 + l16;
        int c0 = et * 16 + q * 4;
        int phys = ((c0 >> 3) ^ (row & 7)) * 8 + (c0 & 7);
        uint2 v;
        v.x = pkbf2(td[et][otl][0], td[et][otl][1]);
        v.y = pkbf2(td[et][otl][2], td[et][otl][3]);
        *(uint2*)(u + row * 64 + phys) = v;
      }
    // B_A2: As visible; h1 loads stay in flight (lgkm only)
    WAIT_LG0(); BARRIER(); SCHEDB();
    // main h0: acc[.][0..3] += As * Bs0 (d-rows 0..127)
#pragma unroll
    for (int k2 = 0; k2 < 2; k2++) {
      bf16x8 af[4], bfr[4];
#pragma unroll
      for (int mf = 0; mf < 4; mf++) {
        int row = wmb * 64 + mf * 16 + l16;
        af[mf] = *(const bf16x8*)(u + row * 64 + (((k2 * 4 + q) ^ (row & 7))) * 8);
      }
#pragma unroll
      for (int nf = 0; nf < 4; nf++) {
        int row = wnh * 64 + nf * 16 + l16;
        bfr[nf] = *(const bf16x8*)(Bs0 + row * 64 + (((k2 * 4 + q) ^ (row & 7))) * 8);
      }
      __builtin_amdgcn_s_setprio(1);
#pragma unroll
      for (int mf = 0; mf < 4; mf++)
#pragma unroll
        for (int nf = 0; nf < 4; nf++)
          acc[mf][nf] = __builtin_amdgcn_mfma_f32_16x16x32_bf16(af[mf], bfr[nf],
                                                                acc[mf][nf], 0, 0, 0);
      __builtin_amdgcn_s_setprio(0);
    }
    // B_B: drains h1 loads (flew during As+h0); Bs0 free for next h0
    WAIT_VM0_LG0(); BARRIER(); SCHEDB();
    if (s < 31) {                            // issue next step's h0 loads
      int sn = s + 1, kn = sn & 3, ecn = sn >> 2;
      const unsigned short* gb = Bt + (size_t)n0 * KK
                                    + (size_t)(kw0 + kn) * 512 + ecn * 64;
#pragma unroll
      for (int j = 0; j < 4; j++)
        gld16((char*)Bs0 + (j * 256 + t) * 16, gb + (size_t)(j * 32 + srow) * KK + cg * 8);
    }
    // main h1: acc[.][4..7] += As * Bs1 (d-rows 128..255)
#pragma unroll
    for (int k2 = 0; k2 < 2; k2++) {
      bf16x8 af[4], bfr[4];
#pragma unroll
      for (int mf = 0; mf < 4; mf++) {
        int row = wmb * 64 + mf * 16 + l16;
        af[mf] = *(const bf16x8*)(u + row * 64 + (((k2 * 4 + q) ^ (row & 7))) * 8);
      }
#pragma unroll
      for (int nf = 0; nf < 4; nf++) {
        int row = wnh * 64 + nf * 16 + l16;
        bfr[nf] = *(const bf16x8*)(Bs1 + row * 64 + (((k2 * 4 + q) ^ (row & 7))) * 8);
      }
      __builtin_amdgcn_s_setprio(1);
#pragma unroll
      for (int mf = 0; mf < 4; mf++)
#pragma unroll
        for (int nf = 0; nf < 4; nf++)
          acc[mf][4 + nf] = __builtin_amdgcn_mfma_f32_16x16x32_bf16(af[mf], bfr[nf],
                                                                    acc[mf][4 + nf], 0, 0, 0);
      __builtin_amdgcn_s_setprio(0);
    }
  }
  // epilogue: n-col = n0 + h*128 + wnh*64 + nfq*16 + l16
#pragma unroll
  for (int mf = 0; mf < 4; mf++)
#pragma unroll
    for (int nf = 0; nf < 8; nf++) {
      int col = n0 + (nf >> 2) * 128 + wnh * 64 + (nf & 3) * 16 + l16;
#pragma unroll
      for (int r = 0; r < 4; r++)
        atomicAdd(&out[(size_t)(m0 + wmb * 64 + mf * 16 + q * 4 + r) * 512 + col],
                  acc[mf][nf][r]);
    }
}

// ---- fp32 fallback (only if ws too small)
__global__ __launch_bounds__(256) void fallback_kern(const float* __restrict__ x,
                                                     const float* __restrict__ W,
                                                     const float* __restrict__ coeff,
                                                     float* __restrict__ out) {
  __shared__ float ev[64][129];
  int b = blockIdx.x >> 6, k = blockIdx.x & 63;
  int t = threadIdx.x, dl = t & 127, half = t >> 7;
  const float* xb = x + (size_t)b * 64 * 512;
  const float* Wk = W + (size_t)k * 512 * 512;
  for (int dc = 0; dc < 4; dc++) {
    int d = dc * 128 + dl;
    for (int i = half * 32; i < half * 32 + 32; i++) {
      float acc = 0.f;
      const float* xr = xb + (size_t)i * 512;
#pragma unroll 4
      for (int e = 0; e < 512; e++) acc += xr[e] * Wk[(size_t)e * 512 + d];
      ev[i][dl] = acc;
    }
    __syncthreads();
    for (int o = half * 32; o < half * 32 + 32; o++) {
      float s = 0.f;
#pragma unroll 8
      for (int i = 0; i < 64; i++) s += coeff[((size_t)o * 64 + i) * 64 + k] * ev[i][dl];
      atomicAdd(&out[((size_t)(b * 64 + o)) * 512 + d], s);
    }
    __syncthreads();
  }
}

extern "C" void kernel_launch(void* const* d_in, const int* in_sizes, int n_in,
                              void* d_out, int out_size, void* d_ws, size_t ws_size,
                              hipStream_t stream) {
  const float* x = (const float*)d_in[0];
  const float* W = (const float*)d_in[1];
  const float* coeff = (const float*)d_in[2];
  float* out = (float*)d_out;
  const size_t OFF_XT = 33554432;            // WbT: 512*32768*2
  const size_t OFF_CB = OFF_XT + 2097152;    // xT : 32*512*64*2
  const size_t NEED = OFF_CB + 524288;       // cb : 64*64*64*2

  if (ws_size >= NEED) {
    unsigned short* WbT = (unsigned short*)d_ws;
    unsigned short* xT  = (unsigned short*)((char*)d_ws + OFF_XT);
    unsigned short* cb  = (unsigned short*)((char*)d_ws + OFF_CB);
    prep_kern<<<2368, 256, 0, stream>>>(x, coeff, W, xT, cb, WbT, out);
    fused_kern<<<512, 256, 0, stream>>>(xT, cb, WbT, out);
  } else {
    hipMemsetAsync(d_out, 0, (size_t)out_size * sizeof(float), stream);
    fallback_kern<<<2048, 256, 0, stream>>>(x, W, coeff, out);
  }
}

// Round 11
// 215.188 us; speedup vs baseline: 1.0110x; 1.0110x over previous
//
#include <hip/hip_runtime.h>
#include <hip/hip_bf16.h>

// Problem: B=32, F_IN=64, F_OUT=64, D=512, K=64
// out[(b,o),d] = sum_{k,e} T[(b,o),(k,e)] * W[k,e,d],
// T[(b,o),(k,e)] = sum_i coeff[o,i,k] * x[b,i,e]
// R20 = R18 exact (best verified: 215.6 us total, fused 122.4 us) — terminal
// consolidation. R19's T-phase setprio removed (measured neutral/≤0).
//
// SESSION LEDGER (why this is the stopping point):
//   fused_kern: 5 structurally distinct schedules -> R9/R13/R14 = 124 us,
//   R15 (BK=32) = 162 (8-way LDS bank conflict), R17 (4 blk/CU) = 160
//   (occupancy never materialized: 252 unified regs/wave caps 2 waves/SIMD).
//   At the fixed point: MfmaUtil 29, VALU 15, LDS ~19, HBM 9.5 — latency/
//   lockstep-bound (m233-class 2-phase stall), not a HW roofline. Escaping
//   needs the full 8-phase port with embedded T-producer (2 attempts: 1 race,
//   1 conflict regression). MFMA floor 41 us.
//   prep_kern: ~23 us ≈ BW floor (114 MB converted). ~70 us = fixed harness
//   cost, invariant across all launch/structure configs (R1-R19).

#define KK 32768

typedef __attribute__((ext_vector_type(8))) short bf16x8;
typedef __attribute__((ext_vector_type(4))) float f32x4;

__device__ __forceinline__ unsigned short f2bf(float f) {
  unsigned int u = __float_as_uint(f);
  return (unsigned short)((u + 0x7FFFu + ((u >> 16) & 1u)) >> 16);  // RNE
}

__device__ __forceinline__ unsigned int pkbf2(float a, float b) {
  __hip_bfloat162 h = __float22bfloat162_rn(make_float2(a, b));  // v_cvt_pk_bf16_f32
  return *(unsigned int*)&h;
}

__device__ __forceinline__ void gld16(void* lds, const void* g) {
  __builtin_amdgcn_global_load_lds((const __attribute__((address_space(1))) void*)g,
                                   (__attribute__((address_space(3))) void*)lds,
                                   16, 0, 0);
}

#define WAIT_VM0_LG0() asm volatile("s_waitcnt vmcnt(0) lgkmcnt(0)" ::: "memory")
#define WAIT_VM4()     asm volatile("s_waitcnt vmcnt(4)" ::: "memory")
#define WAIT_LG0()     asm volatile("s_waitcnt lgkmcnt(0)" ::: "memory")
#define BARRIER()      __builtin_amdgcn_s_barrier()
#define SCHEDB()       __builtin_amdgcn_sched_barrier(0)

// ---- merged preproc + out-zero. Blocks:
//   [0,2048):    W fp32 [64 k][512 e][512 d] -> WbT bf16 [512 d][k*512+e]
//   [2048,2176): x fp32 [32 b][64 i][512 e]  -> xT bf16 [b][e][i]
//   [2176,2240): coeff fp32 [64 o][64 i][64 k] -> cb bf16 [k][o*64+i]
//   [2240,2368): zero out (4 MB, 32 KB/block, float4 stores)
__global__ __launch_bounds__(256) void prep_kern(const float* __restrict__ x,
                                                 const float* __restrict__ c,
                                                 const float* __restrict__ W,
                                                 unsigned short* __restrict__ xT,
                                                 unsigned short* __restrict__ cb,
                                                 unsigned short* __restrict__ WbT,
                                                 float* __restrict__ out) {
  __shared__ float tile[64][133];            // 34 KB
  int bx = blockIdx.x;
  int t = threadIdx.x;
  if (bx < 2048) {
    int k = bx >> 5, et = (bx >> 2) & 7, dq = bx & 3;
    const float* src = W + ((size_t)k * 512 + (size_t)et * 64) * 512 + dq * 128;
    int rr = t >> 5, c4 = t & 31;
#pragma unroll
    for (int p = 0; p < 8; p++) {
      int e = p * 8 + rr;
      *(float4*)&tile[e][c4 * 4] = *(const float4*)(src + (size_t)e * 512 + c4 * 4);
    }
    __syncthreads();
    int ch = t & 7, dr = t >> 3;
#pragma unroll
    for (int p = 0; p < 4; p++) {
      int d = p * 32 + dr, e0 = ch * 8;
      uint4 o4;
      o4.x = pkbf2(tile[e0 + 0][d], tile[e0 + 1][d]);
      o4.y = pkbf2(tile[e0 + 2][d], tile[e0 + 3][d]);
      o4.z = pkbf2(tile[e0 + 4][d], tile[e0 + 5][d]);
      o4.w = pkbf2(tile[e0 + 6][d], tile[e0 + 7][d]);
      *(uint4*)(WbT + (size_t)(dq * 128 + d) * KK + k * 512 + et * 64 + e0) = o4;
    }
  } else if (bx < 2176) {
    int bx2 = bx - 2048;
    int b = bx2 >> 2, ec = bx2 & 3;
    const float* src = x + (size_t)b * 32768 + ec * 128;
    int rr = t >> 5, c4 = t & 31;
#pragma unroll
    for (int p = 0; p < 8; p++) {
      int i = p * 8 + rr;
      *(float4*)&tile[i][c4 * 4] = *(const float4*)(src + (size_t)i * 512 + c4 * 4);
    }
    __syncthreads();
    unsigned short* dst = xT + (size_t)b * 32768 + ec * 128 * 64;
    int ch = t & 7, er = t >> 3;
#pragma unroll
    for (int p = 0; p < 4; p++) {
      int e = p * 32 + er, i0 = ch * 8;
      uint4 o4;
      o4.x = pkbf2(tile[i0 + 0][e], tile[i0 + 1][e]);
      o4.y = pkbf2(tile[i0 + 2][e], tile[i0 + 3][e]);
      o4.z = pkbf2(tile[i0 + 4][e], tile[i0 + 5][e]);
      o4.w = pkbf2(tile[i0 + 6][e], tile[i0 + 7][e]);
      *(uint4*)(dst + e * 64 + i0) = o4;
    }
  } else if (bx < 2240) {
    int rb = bx - 2176;
    unsigned short* lds = (unsigned short*)tile;
    const float* src = c + (size_t)rb * 4096;
#pragma unroll
    for (int j = 0; j < 16; j++) {
      int idx = j * 256 + t;
      int r = idx >> 6, k = idx & 63;
      lds[r * 66 + k] = f2bf(src[idx]);
    }
    __syncthreads();
#pragma unroll
    for (int j = 0; j < 16; j++) {
      int idx = j * 256 + t;
      int k = idx >> 6, r = idx & 63;
      cb[(size_t)k * 4096 + rb * 64 + r] = lds[r * 66 + k];
    }
  } else {
    // zero out: 128 blocks x 32 KB (8192 floats); thread t: 8 x float4
    float* dst = out + (size_t)(bx - 2240) * 8192;
    float4 z = {0.f, 0.f, 0.f, 0.f};
#pragma unroll
    for (int j = 0; j < 8; j++)
      *(float4*)(dst + (size_t)j * 1024 + t * 4) = z;
  }
}

// ---- fused T+GEMM (R13 body, proven 122-124 us): grid 512 = mt(16) x np(2)
// x ks(16); block-tile 128m x 256n, kk-slice 2048. 4 waves, 2 blocks/CU.
// Per (ec,k): T-MFMA -> B_A (vmcnt0: drains h0 loads issued a full phase ago)
// -> issue h1 loads -> As write -> B_A2 (lgkm only) -> main h0
// -> B_B (vmcnt0: drains h1, had As+h0 phase to fly) + issue next h0 -> main h1.
__global__ __launch_bounds__(256, 2) void fused_kern(const unsigned short* __restrict__ xT,
                                                     const unsigned short* __restrict__ cb,
                                                     const unsigned short* __restrict__ Bt,
                                                     float* __restrict__ out) {
  __shared__ unsigned short u[128 * 64];     // xe (per-ec) / As alias, 16 KB
  __shared__ unsigned short Bs0[128 * 64];   // d-rows 0..127, 16 KB
  __shared__ unsigned short Bs1[128 * 64];   // d-rows 128..255, 16 KB
  __shared__ unsigned short ck[4 * 64 * 64]; // 32 KB (4 k-words, whole block)
  int bx = blockIdx.x;                       // ks minor: mt-siblings co-XCD
  int ks = bx & 15, np = (bx >> 4) & 1, mt = bx >> 5;
  int m0 = mt * 128, n0 = np * 256, kw0 = ks * 4, b0 = mt * 2;
  int t = threadIdx.x;
  int wid = t >> 6, lane = t & 63, q = lane >> 4, l16 = lane & 15;
  int wmb = wid & 1;                         // m-half (= b index in T-phase)
  int wnh = wid >> 1;                        // n-half (= o-tile-pair in T-phase)
  int srow = t >> 3;                         // 0..31 staging row
  int cg = (t & 7) ^ (srow & 7);
  // ---- prologue: ck (32 KB, 8 rounds) + Bs0 for s=0 h0 (4 rounds)
  {
    const unsigned short* gc = cb + (size_t)kw0 * 4096;
#pragma unroll
    for (int j = 0; j < 8; j++) {
      int row = j * 32 + srow;               // row = kj*64 + o; row&7 == o&7
      gld16((char*)ck + (j * 256 + t) * 16, gc + (size_t)row * 64 + cg * 8);
    }
    const unsigned short* gb = Bt + (size_t)n0 * KK + (size_t)kw0 * 512; // ec=0,k=0,h0
#pragma unroll
    for (int j = 0; j < 4; j++)
      gld16((char*)Bs0 + (j * 256 + t) * 16, gb + (size_t)(j * 32 + srow) * KK + cg * 8);
  }
  f32x4 acc[4][8] = {};                      // wave 64m x 128n (nf = h*4 + nfq)
  bf16x8 ax[4][2];                           // A[m=e][k=i] frags, held per ec
#pragma unroll 1
  for (int s = 0; s < 32; s++) {
    int k = s & 3, ec = s >> 2;
    f32x4 td[4][2];                          // [et][otl], D[m=e][n=o]
    const unsigned short* ckk = ck + k * 4096;
    if (k != 0) {
      // T-phase BEFORE B_A: overlaps h0 loads still in flight
      bf16x8 bc[2][2];
#pragma unroll
      for (int otl = 0; otl < 2; otl++)
#pragma unroll
        for (int k2 = 0; k2 < 2; k2++) {
          int o = (wnh * 2 + otl) * 16 + l16;
          int s2 = (k2 * 4 + q) ^ (o & 7);
          bc[otl][k2] = *(const bf16x8*)(ckk + o * 64 + s2 * 8);
        }
#pragma unroll
      for (int et = 0; et < 4; et++)
#pragma unroll
        for (int otl = 0; otl < 2; otl++) {
          td[et][otl] = (f32x4){0.f, 0.f, 0.f, 0.f};
#pragma unroll
          for (int k2 = 0; k2 < 2; k2++)
            td[et][otl] = __builtin_amdgcn_mfma_f32_16x16x32_bf16(ax[et][k2], bc[otl][k2],
                                                                  td[et][otl], 0, 0, 0);
        }
      // B_A: drains Bs0(s) loads (flew during h1(s-1)); all waves past As reads
      WAIT_VM0_LG0(); BARRIER(); SCHEDB();
      // issue h1 loads (Bs1 readers all past B_A)
      {
        const unsigned short* gb = Bt + (size_t)(n0 + 128) * KK
                                      + (size_t)(kw0 + k) * 512 + ec * 64;
#pragma unroll
        for (int j = 0; j < 4; j++)
          gld16((char*)Bs1 + (j * 256 + t) * 16, gb + (size_t)(j * 32 + srow) * KK + cg * 8);
      }
    } else {
      // B_A: drains Bs0(s) + (s=0: ck); all waves done with u (As of prev ec)
      WAIT_VM0_LG0(); BARRIER(); SCHEDB();
      // stage xe(ec) into u, then issue h1 loads
#pragma unroll
      for (int j = 0; j < 4; j++) {
        int row = j * 32 + srow;
        int bl = row >> 6, el = row & 63;
        gld16((char*)u + (j * 256 + t) * 16,
              xT + (size_t)(b0 + bl) * 32768 + (size_t)(ec * 64 + el) * 64 + cg * 8);
      }
      {
        const unsigned short* gb = Bt + (size_t)(n0 + 128) * KK
                                      + (size_t)kw0 * 512 + ec * 64;
#pragma unroll
        for (int j = 0; j < 4; j++)
          gld16((char*)Bs1 + (j * 256 + t) * 16, gb + (size_t)(j * 32 + srow) * KK + cg * 8);
      }
      WAIT_VM4(); BARRIER(); SCHEDB();       // xe ready (4 Bs1 loads remain in flight)
      // ax frags for this ec
#pragma unroll
      for (int et = 0; et < 4; et++)
#pragma unroll
        for (int k2 = 0; k2 < 2; k2++) {
          int row = wmb * 64 + et * 16 + l16;
          int s2 = (k2 * 4 + q) ^ (row & 7);
          ax[et][k2] = *(const bf16x8*)(u + row * 64 + s2 * 8);
        }
      // T-phase (k=0)
      bf16x8 bc[2][2];
#pragma unroll
      for (int otl = 0; otl < 2; otl++)
#pragma unroll
        for (int k2 = 0; k2 < 2; k2++) {
          int o = (wnh * 2 + otl) * 16 + l16;
          int s2 = (k2 * 4 + q) ^ (o & 7);
          bc[otl][k2] = *(const bf16x8*)(ckk + o * 64 + s2 * 8);
        }
#pragma unroll
      for (int et = 0; et < 4; et++)
#pragma unroll
        for (int otl = 0; otl < 2; otl++) {
          td[et][otl] = (f32x4){0.f, 0.f, 0.f, 0.f};
#pragma unroll
          for (int k2 = 0; k2 < 2; k2++)
            td[et][otl] = __builtin_amdgcn_mfma_f32_16x16x32_bf16(ax[et][k2], bc[otl][k2],
                                                                  td[et][otl], 0, 0, 0);
        }
      // RACE FIX (R13): all waves must finish their ax reads of u before ANY
      // wave overwrites u with As (waves 0/2 share rows 0..63, 1/3 share
      // 64..127). The 4 Bs1 gld16 stay in flight (lgkm-only wait).
      WAIT_LG0(); BARRIER(); SCHEDB();
    }
    // write As (alias u): row = wmb*64 + (wnh*2+otl)*16 + l16 (bo), col e
#pragma unroll
    for (int et = 0; et < 4; et++)
#pragma unroll
      for (int otl = 0; otl < 2; otl++) {
        int row = wmb * 64 + (wnh * 2 + otl) * 16 + l16;
        int c0 = et * 16 + q * 4;
        int phys = ((c0 >> 3) ^ (row & 7)) * 8 + (c0 & 7);
        uint2 v;
        v.x = pkbf2(td[et][otl][0], td[et][otl][1]);
        v.y = pkbf2(td[et][otl][2], td[et][otl][3]);
        *(uint2*)(u + row * 64 + phys) = v;
      }
    // B_A2: As visible; h1 loads stay in flight (lgkm only)
    WAIT_LG0(); BARRIER(); SCHEDB();
    // main h0: acc[.][0..3] += As * Bs0 (d-rows 0..127)
#pragma unroll
    for (int k2 = 0; k2 < 2; k2++) {
      bf16x8 af[4], bfr[4];
#pragma unroll
      for (int mf = 0; mf < 4; mf++) {
        int row = wmb * 64 + mf * 16 + l16;
        af[mf] = *(const bf16x8*)(u + row * 64 + (((k2 * 4 + q) ^ (row & 7))) * 8);
      }
#pragma unroll
      for (int nf = 0; nf < 4; nf++) {
        int row = wnh * 64 + nf * 16 + l16;
        bfr[nf] = *(const bf16x8*)(Bs0 + row * 64 + (((k2 * 4 + q) ^ (row & 7))) * 8);
      }
      __builtin_amdgcn_s_setprio(1);
#pragma unroll
      for (int mf = 0; mf < 4; mf++)
#pragma unroll
        for (int nf = 0; nf < 4; nf++)
          acc[mf][nf] = __builtin_amdgcn_mfma_f32_16x16x32_bf16(af[mf], bfr[nf],
                                                                acc[mf][nf], 0, 0, 0);
      __builtin_amdgcn_s_setprio(0);
    }
    // B_B: drains h1 loads (flew during As+h0); Bs0 free for next h0
    WAIT_VM0_LG0(); BARRIER(); SCHEDB();
    if (s < 31) {                            // issue next step's h0 loads
      int sn = s + 1, kn = sn & 3, ecn = sn >> 2;
      const unsigned short* gb = Bt + (size_t)n0 * KK
                                    + (size_t)(kw0 + kn) * 512 + ecn * 64;
#pragma unroll
      for (int j = 0; j < 4; j++)
        gld16((char*)Bs0 + (j * 256 + t) * 16, gb + (size_t)(j * 32 + srow) * KK + cg * 8);
    }
    // main h1: acc[.][4..7] += As * Bs1 (d-rows 128..255)
#pragma unroll
    for (int k2 = 0; k2 < 2; k2++) {
      bf16x8 af[4], bfr[4];
#pragma unroll
      for (int mf = 0; mf < 4; mf++) {
        int row = wmb * 64 + mf * 16 + l16;
        af[mf] = *(const bf16x8*)(u + row * 64 + (((k2 * 4 + q) ^ (row & 7))) * 8);
      }
#pragma unroll
      for (int nf = 0; nf < 4; nf++) {
        int row = wnh * 64 + nf * 16 + l16;
        bfr[nf] = *(const bf16x8*)(Bs1 + row * 64 + (((k2 * 4 + q) ^ (row & 7))) * 8);
      }
      __builtin_amdgcn_s_setprio(1);
#pragma unroll
      for (int mf = 0; mf < 4; mf++)
#pragma unroll
        for (int nf = 0; nf < 4; nf++)
          acc[mf][4 + nf] = __builtin_amdgcn_mfma_f32_16x16x32_bf16(af[mf], bfr[nf],
                                                                    acc[mf][4 + nf], 0, 0, 0);
      __builtin_amdgcn_s_setprio(0);
    }
  }
  // epilogue: n-col = n0 + h*128 + wnh*64 + nfq*16 + l16
#pragma unroll
  for (int mf = 0; mf < 4; mf++)
#pragma unroll
    for (int nf = 0; nf < 8; nf++) {
      int col = n0 + (nf >> 2) * 128 + wnh * 64 + (nf & 3) * 16 + l16;
#pragma unroll
      for (int r = 0; r < 4; r++)
        atomicAdd(&out[(size_t)(m0 + wmb * 64 + mf * 16 + q * 4 + r) * 512 + col],
                  acc[mf][nf][r]);
    }
}

// ---- fp32 fallback (only if ws too small)
__global__ __launch_bounds__(256) void fallback_kern(const float* __restrict__ x,
                                                     const float* __restrict__ W,
                                                     const float* __restrict__ coeff,
                                                     float* __restrict__ out) {
  __shared__ float ev[64][129];
  int b = blockIdx.x >> 6, k = blockIdx.x & 63;
  int t = threadIdx.x, dl = t & 127, half = t >> 7;
  const float* xb = x + (size_t)b * 64 * 512;
  const float* Wk = W + (size_t)k * 512 * 512;
  for (int dc = 0; dc < 4; dc++) {
    int d = dc * 128 + dl;
    for (int i = half * 32; i < half * 32 + 32; i++) {
      float acc = 0.f;
      const float* xr = xb + (size_t)i * 512;
#pragma unroll 4
      for (int e = 0; e < 512; e++) acc += xr[e] * Wk[(size_t)e * 512 + d];
      ev[i][dl] = acc;
    }
    __syncthreads();
    for (int o = half * 32; o < half * 32 + 32; o++) {
      float s = 0.f;
#pragma unroll 8
      for (int i = 0; i < 64; i++) s += coeff[((size_t)o * 64 + i) * 64 + k] * ev[i][dl];
      atomicAdd(&out[((size_t)(b * 64 + o)) * 512 + d], s);
    }
    __syncthreads();
  }
}

extern "C" void kernel_launch(void* const* d_in, const int* in_sizes, int n_in,
                              void* d_out, int out_size, void* d_ws, size_t ws_size,
                              hipStream_t stream) {
  const float* x = (const float*)d_in[0];
  const float* W = (const float*)d_in[1];
  const float* coeff = (const float*)d_in[2];
  float* out = (float*)d_out;
  const size_t OFF_XT = 33554432;            // WbT: 512*32768*2
  const size_t OFF_CB = OFF_XT + 2097152;    // xT : 32*512*64*2
  const size_t NEED = OFF_CB + 524288;       // cb : 64*64*64*2

  if (ws_size >= NEED) {
    unsigned short* WbT = (unsigned short*)d_ws;
    unsigned short* xT  = (unsigned short*)((char*)d_ws + OFF_XT);
    unsigned short* cb  = (unsigned short*)((char*)d_ws + OFF_CB);
    prep_kern<<<2368, 256, 0, stream>>>(x, coeff, W, xT, cb, WbT, out);
    fused_kern<<<512, 256, 0, stream>>>(xT, cb, WbT, out);
  } else {
    hipMemsetAsync(d_out, 0, (size_t)out_size * sizeof(float), stream);
    fallback_kern<<<2048, 256, 0, stream>>>(x, W, coeff, out);
  }
}